// Round 10
// baseline (346.877 us; speedup 1.0000x reference)
//
#include <hip/hip_runtime.h>
#include <hip/hip_bf16.h>

#define HW 128
#define GNUM 2
#define BATCH 4
#define OBT_STRIDE (GNUM * 18 * 2 * 512)       // shorts per hi/lo sub-buffer
#define PWT_FLOATS 36864                       // 73728 shorts (f16)
#define OBT_FLOATS 36864                       // 73728 shorts (hi+lo bf16)
#define DWP_WORDS 5184                         // 2g*9tap2*9j*32 u32 (f16x2)

typedef short s16x8 __attribute__((ext_vector_type(8)));
typedef _Float16 f16x8 __attribute__((ext_vector_type(8)));
typedef _Float16 f16x2 __attribute__((ext_vector_type(2)));
typedef __fp16 h16x2 __attribute__((ext_vector_type(2)));   // cvt_pkrtz ret type
typedef float f32x4 __attribute__((ext_vector_type(4)));
typedef float f32x2 __attribute__((ext_vector_type(2)));

__device__ inline unsigned short f2bf(float f) {
    union { float f; unsigned u; } v;
    v.f = f;
    unsigned r = (v.u + 0x7fffu + ((v.u >> 16) & 1u)) >> 16;
    return (unsigned short)r;
}
__device__ inline unsigned pk2bf(float lo, float hi) {   // v_cvt_pk_bf16_f32
    __hip_bfloat162 r = __float22bfloat162_rn(float2{lo, hi});
    return *(unsigned*)&r;
}
__device__ inline float blo(unsigned u) {
    union { unsigned u; float f; } v; v.u = u << 16; return v.f;
}
__device__ inline float bhi(unsigned u) {
    union { unsigned u; float f; } v; v.u = u & 0xffff0000u; return v.f;
}
__device__ inline unsigned short f2h(float f) {
    _Float16 h = (_Float16)f;
    return *(unsigned short*)&h;
}
__device__ inline unsigned pk2h(float lo, float hi) {    // v_cvt_pkrtz_f16_f32
    union { h16x2 h; unsigned u; } v;
    v.h = __builtin_amdgcn_cvt_pkrtz(lo, hi);
    return v.u;
}
__device__ inline f16x2 u2h(unsigned u) {
    union { unsigned u; f16x2 h; } v; v.u = u; return v.h;
}
__device__ inline unsigned h2u(f16x2 h) {
    union { unsigned u; f16x2 h; } v; v.h = h; return v.u;
}
// XOR-swizzle: permute 16B chunks within a 64-short row by (row + row/8) & 7.
__device__ inline int swz(int row, int off) {
    return (off & 7) | ((((off >> 3) ^ (row + (row >> 3))) & 7) << 3);
}

// ---------------------------------------------------------------------------
// prep_kernel (grid 28 x GNUM): unchanged from R8 (validated).
// ---------------------------------------------------------------------------
__global__ __launch_bounds__(256) void prep_kernel(
    const float* __restrict__ pw_w, const float* __restrict__ dw_b,
    const float* __restrict__ off_w, const float* __restrict__ dw_w,
    unsigned short* __restrict__ pwt, unsigned short* __restrict__ obt,
    unsigned* __restrict__ dwp, float* __restrict__ bias2) {
    const int g = blockIdx.y;
    const int t = threadIdx.x;
    if (blockIdx.x < 9) {
        const int j = blockIdx.x;
        const int wv = t >> 6, lane = t & 63;
        const int f = wv * 16 + (lane & 15);
        const int kbase = (lane >> 4) << 3;
#pragma unroll
        for (int ks = 0; ks < 2; ++ks)
#pragma unroll
            for (int i = 0; i < 8; ++i) {
                int kin = j * 64 + ks * 32 + kbase + i;
                pwt[((((g * 9 + j) * 4 + wv) * 2 + ks) << 9) + lane * 8 + i] =
                    f2h(pw_w[(g * 576 + kin) * 64 + f]);
            }
        for (int e = t; e < 288; e += 256) {
            int tap2 = e >> 5, cp = e & 31;
            const float* dwr = &dw_w[(g * 9 + tap2) * 576 + (j << 6) + cp * 2];
            dwp[(((g * 9 + tap2) * 9 + j) << 5) + cp] = pk2h(dwr[0], dwr[1]);
        }
    } else if (blockIdx.x < 27) {
        const int s = blockIdx.x - 9;
        const int tap = s >> 1;
        for (int e = t; e < 1024; e += 256) {
            int nt = e >> 9, le = e & 511;
            int lane = le >> 3, i = le & 7;
            int k = ((lane >> 4) << 3) + i;
            int c = ((s & 1) << 5) + k;
            int n = (nt << 4) + (lane & 15);
            float v = (n < 18) ? off_w[((g * 9 + tap) * 64 + c) * 18 + n] : 0.f;
            unsigned short hi = f2bf(v);
            unsigned short lo = f2bf(v - blo(hi));
            int idx = (((g * 18 + s) * 2 + nt) << 9) + le;
            obt[idx] = hi;
            obt[OBT_STRIDE + idx] = lo;
        }
    } else {
        if (t < 64) {
            float s = 0.f;
            for (int kin = 0; kin < 576; ++kin)
                s += pw_w[(g * 576 + kin) * 64 + t] * dw_b[g * 576 + kin];
            bias2[g * 64 + t] = s;
        }
    }
}

// S-phase gather issue: load all 28 float4 corners for tap JJ into rv[][].
// Static indices after unroll -> registers (rule #20).  it<6 always valid;
// it==6 clamps sp for the address (write is guarded at blend).
#define S_ISSUE(JJ)                                                          \
    _Pragma("unroll")                                                        \
    for (int it = 0; it < 7; ++it) {                                         \
        int sp_ = (it << 4) + grp;                                           \
        int spc = sp_ < 100 ? sp_ : 99;                                      \
        unsigned wp = wliAll[(JJ) * 100 + spc];                              \
        const float* xa = x + (wp & 0xFFFFFF80u) + (g << 6) + (sl16 << 2);   \
        const int xo = (int)((wp & 1u) << 7);                                \
        const int yo = (int)((wp & 2u) << 13);                               \
        rv[it][0] = *(const float4*)xa;                                      \
        rv[it][1] = *(const float4*)(xa + yo);                               \
        rv[it][2] = *(const float4*)(xa + xo);                               \
        rv[it][3] = *(const float4*)(xa + xo + yo);                          \
    }

// ---------------------------------------------------------------------------
// deform_fused (R10 = R9 + T14 cross-tap register prefetch of the S gathers):
//   per tap: BLEND(j) from regs -> samp; ISSUE(j+1) 28 loads (land during
//   A+B+barriers); barrier; A (depthwise); barrier; B (MFMA).
//   VGPR ~160 -> 3 blocks/CU (12 waves); launch_bounds(256,3).
// LDS 38,992 B (layout unchanged from R9):
//   [0,18432):  xh ushort[144*64] (stage 0)  ALIASED WITH offs float[100*18]
//               (epilogue) and samp ushort[100*64] (j-loop)
//   [12800,20992): dwa ushort[64*64] (j-loop)
//   [20992,35392): wlwAll float4[900] ; [35392,38992): wliAll unsigned[900]
// ---------------------------------------------------------------------------
__global__ __launch_bounds__(256, 3) void deform_fused(
    const float* __restrict__ x, const unsigned short* __restrict__ obt,
    const float* __restrict__ off_b, const unsigned* __restrict__ dwp,
    const unsigned short* __restrict__ pwt, const float* __restrict__ bias2,
    const float* __restrict__ pw_b, float* __restrict__ out) {
    __shared__ char smem[38992];
    unsigned short* xh = (unsigned short*)smem;            // stage 0 only
    float* offs = (float*)smem;                            // epilogue only
    unsigned short* samp = (unsigned short*)smem;          // j-loop
    unsigned short* dwa = (unsigned short*)(smem + 12800); // j-loop
    float4* wlwAll = (float4*)(smem + 20992);
    unsigned* wliAll = (unsigned*)(smem + 35392);

    const int b = blockIdx.x >> 1, g = blockIdx.x & 1;
    const int tileIdx = blockIdx.y;
    const int h0 = (tileIdx >> 4) << 3, w0 = (tileIdx & 15) << 3;
    const int t = threadIdx.x;
    const int lane = t & 63;
    const int wv = __builtin_amdgcn_readfirstlane(t >> 6);
    const int kq = (lane >> 4) << 3;
    const int col = lane & 15;
    const int rq = (lane >> 4) << 2;

    // ================= Stage 0: offset conv for the halo =================
    f32x4 oacc[2][2];
#pragma unroll
    for (int sl = 0; sl < 2; ++sl)
#pragma unroll
        for (int nt = 0; nt < 2; ++nt) oacc[sl][nt] = (f32x4){0.f, 0.f, 0.f, 0.f};
    int mbase[2];
#pragma unroll
    for (int sl = 0; sl < 2; ++sl) {
        int mt = wv + (sl << 2);
        int m = mt * 16 + col;
        if (mt < 7 && m < 100) {
            int opy = m / 10, opx = m - opy * 10;
            mbase[sl] = opy * 12 + opx;
        } else
            mbase[sl] = 0;
    }
    for (int q = 0; q < 2; ++q) {
        if (q) __syncthreads();
        for (int idx = t; idx < 144 * 8; idx += 256) {
            int sp = idx >> 3, cq = idx & 7;
            int sy = sp / 12, sx = sp - sy * 12;
            int gy = h0 - 2 + sy, gx = w0 - 2 + sx;
            uint2 hp = {0, 0}, lp = {0, 0};
            if ((unsigned)gy < HW && (unsigned)gx < HW) {
                const float4 v = *(const float4*)&x[(((b * HW + gy) * HW + gx)
                                                    << 7) +
                                                   (g << 6) + (q << 5) + (cq << 2)];
                hp.x = pk2bf(v.x, v.y);
                hp.y = pk2bf(v.z, v.w);
                lp.x = pk2bf(v.x - blo(hp.x), v.y - bhi(hp.x));
                lp.y = pk2bf(v.z - blo(hp.y), v.w - bhi(hp.y));
            }
            *(uint2*)&xh[sp * 64 + swz(sp, cq << 2)] = hp;
            *(uint2*)&xh[sp * 64 + swz(sp, 32 + (cq << 2))] = lp;
        }
        __syncthreads();
        for (int tap = 0; tap < 9; ++tap) {
            const int s = (tap << 1) + q;
            const int ky = tap / 3, kx = tap - ky * 3;
            const int shift = ky * 12 + kx;
            const int bidx = ((g * 18 + s) << 1) << 9;
            s16x8 bh0 = *(const s16x8*)&obt[bidx + lane * 8];
            s16x8 bh1 = *(const s16x8*)&obt[bidx + 512 + lane * 8];
            s16x8 bl0 = *(const s16x8*)&obt[OBT_STRIDE + bidx + lane * 8];
            s16x8 bl1 = *(const s16x8*)&obt[OBT_STRIDE + bidx + 512 + lane * 8];
#pragma unroll
            for (int sl = 0; sl < 2; ++sl) {
                if (wv + (sl << 2) < 7) {   // wave-uniform guard
                    const int m2 = mbase[sl] + shift;
                    s16x8 ah = *(const s16x8*)&xh[m2 * 64 + swz(m2, kq)];
                    s16x8 al = *(const s16x8*)&xh[m2 * 64 + swz(m2, kq + 32)];
                    oacc[sl][0] = __builtin_amdgcn_mfma_f32_16x16x32_bf16(
                        ah, bh0, oacc[sl][0], 0, 0, 0);
                    oacc[sl][1] = __builtin_amdgcn_mfma_f32_16x16x32_bf16(
                        ah, bh1, oacc[sl][1], 0, 0, 0);
                    oacc[sl][0] = __builtin_amdgcn_mfma_f32_16x16x32_bf16(
                        al, bh0, oacc[sl][0], 0, 0, 0);
                    oacc[sl][1] = __builtin_amdgcn_mfma_f32_16x16x32_bf16(
                        al, bh1, oacc[sl][1], 0, 0, 0);
                    oacc[sl][0] = __builtin_amdgcn_mfma_f32_16x16x32_bf16(
                        ah, bl0, oacc[sl][0], 0, 0, 0);
                    oacc[sl][1] = __builtin_amdgcn_mfma_f32_16x16x32_bf16(
                        ah, bl1, oacc[sl][1], 0, 0, 0);
                }
            }
        }
    }
    __syncthreads();   // all xh reads done: offs aliases xh rows 0..56
    // write offs[m][o] = conv + off_b   (C-layout: row = rq+i, col)
#pragma unroll
    for (int sl = 0; sl < 2; ++sl) {
        int mt = wv + (sl << 2);
        if (mt < 7) {
#pragma unroll
            for (int nt = 0; nt < 2; ++nt) {
                int o = (nt << 4) + col;
                if (o < 18) {
                    float ob = off_b[g * 18 + o];
#pragma unroll
                    for (int i = 0; i < 4; ++i) {
                        int m = mt * 16 + rq + i;
                        if (m < 100) offs[m * 18 + o] = oacc[sl][nt][i] + ob;
                    }
                }
            }
        }
    }
    __syncthreads();   // offs visible
    // ---- W-precompute: bilinear weights + packed corners, ALL 9 taps ----
    for (int e = t; e < 900; e += 256) {
        const int jj = e / 100, sp = e - jj * 100;
        const int jy = jj / 3, jx = jj - jy * 3;
        const int spy = sp / 10, spx = sp - spy * 10;
        const int gy = h0 - 1 + spy, gx = w0 - 1 + spx;
        float4 w4 = {0.f, 0.f, 0.f, 0.f};
        unsigned wp = (unsigned)(b << 21);
        if ((unsigned)gy < HW && (unsigned)gx < HW) {
            const float ox = offs[sp * 18 + 2 * jj];
            const float oy = offs[sp * 18 + 2 * jj + 1];
            float xf = fminf(fmaxf((float)(gx + jx - 1) + ox, 0.f), 127.f);
            float yf = fminf(fmaxf((float)(gy + jy - 1) + oy, 0.f), 127.f);
            float x0 = floorf(xf), y0 = floorf(yf);
            float x1 = fminf(x0 + 1.f, 127.f);
            float y1 = fminf(y0 + 1.f, 127.f);
            w4.x = (x1 - xf) * (y1 - yf);
            w4.y = (x1 - xf) * (yf - y0);
            w4.z = (xf - x0) * (y1 - yf);
            w4.w = (xf - x0) * (yf - y0);
            const int x0i = (int)x0, y0i = (int)y0;
            wp = (unsigned)(((b * HW + y0i) * HW + x0i) << 7) |
                 (unsigned)((int)x1 - x0i) |
                 ((unsigned)((int)y1 - y0i) << 1);
        }
        wlwAll[jj * 100 + sp] = w4;
        wliAll[jj * 100 + sp] = wp;
    }
    __syncthreads();   // wlwAll/wliAll visible; offs dead

    // ================= Stage 1: sample -> depthwise -> pointwise =========
    const int fb = wv << 4;
    const int p = lane;
    const int ayp = p >> 3, axp = p & 7;
    const int grp = t >> 4, sl16 = t & 15;
    const int prow = ayp * 10 + axp;

    // hoisted j-invariant LDS offsets (static-indexed -> VGPRs)
    int aoff[9][2];
#pragma unroll
    for (int t2 = 0; t2 < 9; ++t2) {
        const int ky = t2 / 3, kx = t2 - ky * 3;
        const int row = prow + ky * 10 + kx;
#pragma unroll
        for (int cq = 0; cq < 2; ++cq)
            aoff[t2][cq] = row * 64 + swz(row, fb + (cq << 3));
    }
    int boff[2][4];
#pragma unroll
    for (int ks = 0; ks < 2; ++ks)
#pragma unroll
        for (int mt = 0; mt < 4; ++mt) {
            const int row = mt * 16 + col;
            boff[ks][mt] = row * 64 + swz(row, ks * 32 + kq);
        }

    const float bs = bias2[g * 64 + fb + col] + pw_b[g * 64 + fb + col];
    f32x4 acc[4];
#pragma unroll
    for (int mt = 0; mt < 4; ++mt) acc[mt] = (f32x4){bs, bs, bs, bs};

    float4 rv[7][4];   // prefetched gather corners (static indexing only)
    S_ISSUE(0);        // prologue: tap 0 loads in flight

    for (int j = 0; j < 9; ++j) {
        // ---- Phase S-blend: consume rv (tap j), write samp
#pragma unroll
        for (int it = 0; it < 7; ++it) {
            const int sp = (it << 4) + grp;
            if (it < 6 || grp < 4) {
                const float4 w4 = wlwAll[j * 100 + sp];
                f32x2 a01 = {rv[it][0].x, rv[it][0].y};
                f32x2 b01 = {rv[it][1].x, rv[it][1].y};
                f32x2 c01 = {rv[it][2].x, rv[it][2].y};
                f32x2 d01 = {rv[it][3].x, rv[it][3].y};
                f32x2 a23 = {rv[it][0].z, rv[it][0].w};
                f32x2 b23 = {rv[it][1].z, rv[it][1].w};
                f32x2 c23 = {rv[it][2].z, rv[it][2].w};
                f32x2 d23 = {rv[it][3].z, rv[it][3].w};
                f32x2 r01 = w4.x * a01 + w4.y * b01 + w4.z * c01 + w4.w * d01;
                f32x2 r23 = w4.x * a23 + w4.y * b23 + w4.z * c23 + w4.w * d23;
                uint2 pk;
                pk.x = pk2h(r01.x, r01.y);
                pk.y = pk2h(r23.x, r23.y);
                *(uint2*)&samp[sp * 64 + swz(sp, sl16 << 2)] = pk;
            }
        }
        // ---- issue next tap's gathers; land during A+B+barriers (T14)
        if (j < 8) { S_ISSUE(j + 1); }
        f16x8 bfr[2];
#pragma unroll
        for (int ks = 0; ks < 2; ++ks)
            bfr[ks] = *(const f16x8*)&pwt[((((g * 9 + j) * 4 + wv) * 2 + ks)
                                           << 9) + lane * 8];
        __syncthreads();
        // ---- Phase A: depthwise 3x3 via packed f16 FMA, ch [fb, fb+16)
#pragma unroll
        for (int cq = 0; cq < 2; ++cq) {
            const int c8 = fb + (cq << 3);
            f16x2 d0 = {0, 0}, d1 = {0, 0}, d2 = {0, 0}, d3 = {0, 0};
#pragma unroll
            for (int t2 = 0; t2 < 9; ++t2) {
                const uint4 hv = *(const uint4*)&samp[aoff[t2][cq]];
                const uint4 wq =
                    *(const uint4*)&dwp[(((g * 9 + t2) * 9 + j) << 5) +
                                        (c8 >> 1)];
                d0 = u2h(hv.x) * u2h(wq.x) + d0;   // v_pk_fma_f16
                d1 = u2h(hv.y) * u2h(wq.y) + d1;
                d2 = u2h(hv.z) * u2h(wq.z) + d2;
                d3 = u2h(hv.w) * u2h(wq.w) + d3;
            }
            uint4 pk;
            pk.x = h2u(d0);
            pk.y = h2u(d1);
            pk.z = h2u(d2);
            pk.w = h2u(d3);
            *(uint4*)&dwa[p * 64 + swz(p, c8)] = pk;
        }
        __syncthreads();
        // ---- Phase B: pointwise via f16 MFMA
#pragma unroll
        for (int ks = 0; ks < 2; ++ks)
#pragma unroll
            for (int mt = 0; mt < 4; ++mt) {
                f16x8 af = *(const f16x8*)&dwa[boff[ks][mt]];
                acc[mt] = __builtin_amdgcn_mfma_f32_16x16x32_f16(
                    af, bfr[ks], acc[mt], 0, 0, 0);
            }
    }
    // ---- epilogue: C-layout col=lane&15, row=(lane>>4)*4+i
#pragma unroll
    for (int mt = 0; mt < 4; ++mt)
#pragma unroll
        for (int i = 0; i < 4; ++i) {
            int m = mt * 16 + rq + i;
            out[((b * HW + h0 + (m >> 3)) * HW + (w0 + (m & 7))) * 128 +
                (g << 6) + fb + col] = acc[mt][i];
        }
}

extern "C" void kernel_launch(void* const* d_in, const int* in_sizes, int n_in,
                              void* d_out, int out_size, void* d_ws,
                              size_t ws_size, hipStream_t stream) {
    const float* x = (const float*)d_in[0];
    const float* off_w = (const float*)d_in[1];
    const float* off_b = (const float*)d_in[2];
    const float* dw_w = (const float*)d_in[3];
    const float* dw_b = (const float*)d_in[4];
    const float* pw_w = (const float*)d_in[5];
    const float* pw_b = (const float*)d_in[6];

    // workspace layout (floats): [pwt | obt | dwp | bias2]
    float* wsf = (float*)d_ws;
    unsigned short* pwt = (unsigned short*)wsf;                // 147456 B
    unsigned short* obt = (unsigned short*)(wsf + PWT_FLOATS); // 147456 B
    unsigned* dwp = (unsigned*)(wsf + PWT_FLOATS + OBT_FLOATS);// 20736 B
    float* bias2 = wsf + PWT_FLOATS + OBT_FLOATS + DWP_WORDS;  // 512 B

    prep_kernel<<<dim3(28, GNUM), dim3(256), 0, stream>>>(pw_w, dw_b, off_w,
                                                          dw_w, pwt, obt, dwp,
                                                          bias2);
    deform_fused<<<dim3(BATCH * GNUM, 256), dim3(256), 0, stream>>>(
        x, obt, off_b, dwp, pwt, bias2, pw_b, (float*)d_out);
}

// Round 11
// 226.180 us; speedup vs baseline: 1.5336x; 1.5336x over previous
//
#include <hip/hip_runtime.h>
#include <hip/hip_bf16.h>

#define HW 128
#define GNUM 2
#define BATCH 4
#define OBT_STRIDE (GNUM * 18 * 2 * 512)       // shorts per hi/lo sub-buffer
#define PWT_FLOATS 36864                       // 73728 shorts (f16)
#define OBT_FLOATS 36864                       // 73728 shorts (hi+lo bf16)
#define DWP_WORDS 5184                         // 2g*9tap2*9j*32 u32 (f16x2)

typedef short s16x8 __attribute__((ext_vector_type(8)));
typedef _Float16 f16x8 __attribute__((ext_vector_type(8)));
typedef _Float16 f16x2 __attribute__((ext_vector_type(2)));
typedef __fp16 h16x2 __attribute__((ext_vector_type(2)));   // cvt_pkrtz ret type
typedef float f32x4 __attribute__((ext_vector_type(4)));
typedef float f32x2 __attribute__((ext_vector_type(2)));

__device__ inline unsigned short f2bf(float f) {
    union { float f; unsigned u; } v;
    v.f = f;
    unsigned r = (v.u + 0x7fffu + ((v.u >> 16) & 1u)) >> 16;
    return (unsigned short)r;
}
__device__ inline unsigned pk2bf(float lo, float hi) {   // v_cvt_pk_bf16_f32
    __hip_bfloat162 r = __float22bfloat162_rn(float2{lo, hi});
    return *(unsigned*)&r;
}
__device__ inline float blo(unsigned u) {
    union { unsigned u; float f; } v; v.u = u << 16; return v.f;
}
__device__ inline float bhi(unsigned u) {
    union { unsigned u; float f; } v; v.u = u & 0xffff0000u; return v.f;
}
__device__ inline unsigned short f2h(float f) {
    _Float16 h = (_Float16)f;
    return *(unsigned short*)&h;
}
__device__ inline unsigned pk2h(float lo, float hi) {    // v_cvt_pkrtz_f16_f32
    union { h16x2 h; unsigned u; } v;
    v.h = __builtin_amdgcn_cvt_pkrtz(lo, hi);
    return v.u;
}
__device__ inline f16x2 u2h(unsigned u) {
    union { unsigned u; f16x2 h; } v; v.u = u; return v.h;
}
__device__ inline unsigned h2u(f16x2 h) {
    union { unsigned u; f16x2 h; } v; v.h = h; return v.u;
}
// XOR-swizzle: permute 16B chunks within a 64-short row by (row + row/8) & 7.
__device__ inline int swz(int row, int off) {
    return (off & 7) | ((((off >> 3) ^ (row + (row >> 3))) & 7) << 3);
}

// ---------------------------------------------------------------------------
// prep_kernel (grid 28 x GNUM): unchanged from R8 (validated).
// ---------------------------------------------------------------------------
__global__ __launch_bounds__(256) void prep_kernel(
    const float* __restrict__ pw_w, const float* __restrict__ dw_b,
    const float* __restrict__ off_w, const float* __restrict__ dw_w,
    unsigned short* __restrict__ pwt, unsigned short* __restrict__ obt,
    unsigned* __restrict__ dwp, float* __restrict__ bias2) {
    const int g = blockIdx.y;
    const int t = threadIdx.x;
    if (blockIdx.x < 9) {
        const int j = blockIdx.x;
        const int wv = t >> 6, lane = t & 63;
        const int f = wv * 16 + (lane & 15);
        const int kbase = (lane >> 4) << 3;
#pragma unroll
        for (int ks = 0; ks < 2; ++ks)
#pragma unroll
            for (int i = 0; i < 8; ++i) {
                int kin = j * 64 + ks * 32 + kbase + i;
                pwt[((((g * 9 + j) * 4 + wv) * 2 + ks) << 9) + lane * 8 + i] =
                    f2h(pw_w[(g * 576 + kin) * 64 + f]);
            }
        for (int e = t; e < 288; e += 256) {
            int tap2 = e >> 5, cp = e & 31;
            const float* dwr = &dw_w[(g * 9 + tap2) * 576 + (j << 6) + cp * 2];
            dwp[(((g * 9 + tap2) * 9 + j) << 5) + cp] = pk2h(dwr[0], dwr[1]);
        }
    } else if (blockIdx.x < 27) {
        const int s = blockIdx.x - 9;
        const int tap = s >> 1;
        for (int e = t; e < 1024; e += 256) {
            int nt = e >> 9, le = e & 511;
            int lane = le >> 3, i = le & 7;
            int k = ((lane >> 4) << 3) + i;
            int c = ((s & 1) << 5) + k;
            int n = (nt << 4) + (lane & 15);
            float v = (n < 18) ? off_w[((g * 9 + tap) * 64 + c) * 18 + n] : 0.f;
            unsigned short hi = f2bf(v);
            unsigned short lo = f2bf(v - blo(hi));
            int idx = (((g * 18 + s) * 2 + nt) << 9) + le;
            obt[idx] = hi;
            obt[OBT_STRIDE + idx] = lo;
        }
    } else {
        if (t < 64) {
            float s = 0.f;
            for (int kin = 0; kin < 576; ++kin)
                s += pw_w[(g * 576 + kin) * 64 + t] * dw_b[g * 576 + kin];
            bias2[g * 64 + t] = s;
        }
    }
}

// ---------------------------------------------------------------------------
// deform_fused (R11 = R9 + WITHIN-PHASE batched S gathers):
//   R10 lesson: cross-phase prefetch (rv live across A+B) spilled to scratch
//   (VGPR 84, FETCH 156MB).  R11 batches all 28 loads at the TOP of phase S
//   and consumes them in the same phase -> live range ends before A; peak
//   ~164 VGPR fits the 3-waves/EU budget.  launch_bounds(256,3).
// LDS 38,992 B (layout unchanged from R9); residency 3 blocks/CU (VGPR-capped).
// ---------------------------------------------------------------------------
__global__ __launch_bounds__(256, 3) void deform_fused(
    const float* __restrict__ x, const unsigned short* __restrict__ obt,
    const float* __restrict__ off_b, const unsigned* __restrict__ dwp,
    const unsigned short* __restrict__ pwt, const float* __restrict__ bias2,
    const float* __restrict__ pw_b, float* __restrict__ out) {
    __shared__ char smem[38992];
    unsigned short* xh = (unsigned short*)smem;            // stage 0 only
    float* offs = (float*)smem;                            // epilogue only
    unsigned short* samp = (unsigned short*)smem;          // j-loop
    unsigned short* dwa = (unsigned short*)(smem + 12800); // j-loop
    float4* wlwAll = (float4*)(smem + 20992);
    unsigned* wliAll = (unsigned*)(smem + 35392);

    const int b = blockIdx.x >> 1, g = blockIdx.x & 1;
    const int tileIdx = blockIdx.y;
    const int h0 = (tileIdx >> 4) << 3, w0 = (tileIdx & 15) << 3;
    const int t = threadIdx.x;
    const int lane = t & 63;
    const int wv = __builtin_amdgcn_readfirstlane(t >> 6);
    const int kq = (lane >> 4) << 3;
    const int col = lane & 15;
    const int rq = (lane >> 4) << 2;

    // ================= Stage 0: offset conv for the halo =================
    f32x4 oacc[2][2];
#pragma unroll
    for (int sl = 0; sl < 2; ++sl)
#pragma unroll
        for (int nt = 0; nt < 2; ++nt) oacc[sl][nt] = (f32x4){0.f, 0.f, 0.f, 0.f};
    int mbase[2];
#pragma unroll
    for (int sl = 0; sl < 2; ++sl) {
        int mt = wv + (sl << 2);
        int m = mt * 16 + col;
        if (mt < 7 && m < 100) {
            int opy = m / 10, opx = m - opy * 10;
            mbase[sl] = opy * 12 + opx;
        } else
            mbase[sl] = 0;
    }
    for (int q = 0; q < 2; ++q) {
        if (q) __syncthreads();
        for (int idx = t; idx < 144 * 8; idx += 256) {
            int sp = idx >> 3, cq = idx & 7;
            int sy = sp / 12, sx = sp - sy * 12;
            int gy = h0 - 2 + sy, gx = w0 - 2 + sx;
            uint2 hp = {0, 0}, lp = {0, 0};
            if ((unsigned)gy < HW && (unsigned)gx < HW) {
                const float4 v = *(const float4*)&x[(((b * HW + gy) * HW + gx)
                                                    << 7) +
                                                   (g << 6) + (q << 5) + (cq << 2)];
                hp.x = pk2bf(v.x, v.y);
                hp.y = pk2bf(v.z, v.w);
                lp.x = pk2bf(v.x - blo(hp.x), v.y - bhi(hp.x));
                lp.y = pk2bf(v.z - blo(hp.y), v.w - bhi(hp.y));
            }
            *(uint2*)&xh[sp * 64 + swz(sp, cq << 2)] = hp;
            *(uint2*)&xh[sp * 64 + swz(sp, 32 + (cq << 2))] = lp;
        }
        __syncthreads();
        for (int tap = 0; tap < 9; ++tap) {
            const int s = (tap << 1) + q;
            const int ky = tap / 3, kx = tap - ky * 3;
            const int shift = ky * 12 + kx;
            const int bidx = ((g * 18 + s) << 1) << 9;
            s16x8 bh0 = *(const s16x8*)&obt[bidx + lane * 8];
            s16x8 bh1 = *(const s16x8*)&obt[bidx + 512 + lane * 8];
            s16x8 bl0 = *(const s16x8*)&obt[OBT_STRIDE + bidx + lane * 8];
            s16x8 bl1 = *(const s16x8*)&obt[OBT_STRIDE + bidx + 512 + lane * 8];
#pragma unroll
            for (int sl = 0; sl < 2; ++sl) {
                if (wv + (sl << 2) < 7) {   // wave-uniform guard
                    const int m2 = mbase[sl] + shift;
                    s16x8 ah = *(const s16x8*)&xh[m2 * 64 + swz(m2, kq)];
                    s16x8 al = *(const s16x8*)&xh[m2 * 64 + swz(m2, kq + 32)];
                    oacc[sl][0] = __builtin_amdgcn_mfma_f32_16x16x32_bf16(
                        ah, bh0, oacc[sl][0], 0, 0, 0);
                    oacc[sl][1] = __builtin_amdgcn_mfma_f32_16x16x32_bf16(
                        ah, bh1, oacc[sl][1], 0, 0, 0);
                    oacc[sl][0] = __builtin_amdgcn_mfma_f32_16x16x32_bf16(
                        al, bh0, oacc[sl][0], 0, 0, 0);
                    oacc[sl][1] = __builtin_amdgcn_mfma_f32_16x16x32_bf16(
                        al, bh1, oacc[sl][1], 0, 0, 0);
                    oacc[sl][0] = __builtin_amdgcn_mfma_f32_16x16x32_bf16(
                        ah, bl0, oacc[sl][0], 0, 0, 0);
                    oacc[sl][1] = __builtin_amdgcn_mfma_f32_16x16x32_bf16(
                        ah, bl1, oacc[sl][1], 0, 0, 0);
                }
            }
        }
    }
    __syncthreads();   // all xh reads done: offs aliases xh rows 0..56
    // write offs[m][o] = conv + off_b   (C-layout: row = rq+i, col)
#pragma unroll
    for (int sl = 0; sl < 2; ++sl) {
        int mt = wv + (sl << 2);
        if (mt < 7) {
#pragma unroll
            for (int nt = 0; nt < 2; ++nt) {
                int o = (nt << 4) + col;
                if (o < 18) {
                    float ob = off_b[g * 18 + o];
#pragma unroll
                    for (int i = 0; i < 4; ++i) {
                        int m = mt * 16 + rq + i;
                        if (m < 100) offs[m * 18 + o] = oacc[sl][nt][i] + ob;
                    }
                }
            }
        }
    }
    __syncthreads();   // offs visible
    // ---- W-precompute: bilinear weights + packed corners, ALL 9 taps ----
    for (int e = t; e < 900; e += 256) {
        const int jj = e / 100, sp = e - jj * 100;
        const int jy = jj / 3, jx = jj - jy * 3;
        const int spy = sp / 10, spx = sp - spy * 10;
        const int gy = h0 - 1 + spy, gx = w0 - 1 + spx;
        float4 w4 = {0.f, 0.f, 0.f, 0.f};
        unsigned wp = (unsigned)(b << 21);
        if ((unsigned)gy < HW && (unsigned)gx < HW) {
            const float ox = offs[sp * 18 + 2 * jj];
            const float oy = offs[sp * 18 + 2 * jj + 1];
            float xf = fminf(fmaxf((float)(gx + jx - 1) + ox, 0.f), 127.f);
            float yf = fminf(fmaxf((float)(gy + jy - 1) + oy, 0.f), 127.f);
            float x0 = floorf(xf), y0 = floorf(yf);
            float x1 = fminf(x0 + 1.f, 127.f);
            float y1 = fminf(y0 + 1.f, 127.f);
            w4.x = (x1 - xf) * (y1 - yf);
            w4.y = (x1 - xf) * (yf - y0);
            w4.z = (xf - x0) * (y1 - yf);
            w4.w = (xf - x0) * (yf - y0);
            const int x0i = (int)x0, y0i = (int)y0;
            wp = (unsigned)(((b * HW + y0i) * HW + x0i) << 7) |
                 (unsigned)((int)x1 - x0i) |
                 ((unsigned)((int)y1 - y0i) << 1);
        }
        wlwAll[jj * 100 + sp] = w4;
        wliAll[jj * 100 + sp] = wp;
    }
    __syncthreads();   // wlwAll/wliAll visible; offs dead

    // ================= Stage 1: sample -> depthwise -> pointwise =========
    const int fb = wv << 4;
    const int p = lane;
    const int ayp = p >> 3, axp = p & 7;
    const int grp = t >> 4, sl16 = t & 15;
    const int prow = ayp * 10 + axp;

    // hoisted j-invariant LDS offsets (static-indexed -> VGPRs)
    int aoff[9][2];
#pragma unroll
    for (int t2 = 0; t2 < 9; ++t2) {
        const int ky = t2 / 3, kx = t2 - ky * 3;
        const int row = prow + ky * 10 + kx;
#pragma unroll
        for (int cq = 0; cq < 2; ++cq)
            aoff[t2][cq] = row * 64 + swz(row, fb + (cq << 3));
    }
    int boff[2][4];
#pragma unroll
    for (int ks = 0; ks < 2; ++ks)
#pragma unroll
        for (int mt = 0; mt < 4; ++mt) {
            const int row = mt * 16 + col;
            boff[ks][mt] = row * 64 + swz(row, ks * 32 + kq);
        }

    const float bs = bias2[g * 64 + fb + col] + pw_b[g * 64 + fb + col];
    f32x4 acc[4];
#pragma unroll
    for (int mt = 0; mt < 4; ++mt) acc[mt] = (f32x4){bs, bs, bs, bs};

    for (int j = 0; j < 9; ++j) {
        // ---- Phase S: batch-issue ALL 28 gathers (clamped addrs, no
        //      guard), then blend.  rv dies at end of phase (no spill).
        {
            float4 rv[7][4];
#pragma unroll
            for (int it = 0; it < 7; ++it) {
                int sp_ = (it << 4) + grp;
                int spc = sp_ < 100 ? sp_ : 99;
                unsigned wp = wliAll[j * 100 + spc];
                const float* xa = x + (wp & 0xFFFFFF80u) + (g << 6) +
                                  (sl16 << 2);
                const int xo = (int)((wp & 1u) << 7);
                const int yo = (int)((wp & 2u) << 13);
                rv[it][0] = *(const float4*)xa;
                rv[it][1] = *(const float4*)(xa + yo);
                rv[it][2] = *(const float4*)(xa + xo);
                rv[it][3] = *(const float4*)(xa + xo + yo);
            }
#pragma unroll
            for (int it = 0; it < 7; ++it) {
                const int sp = (it << 4) + grp;
                if (it < 6 || grp < 4) {
                    const float4 w4 = wlwAll[j * 100 + sp];
                    f32x2 a01 = {rv[it][0].x, rv[it][0].y};
                    f32x2 b01 = {rv[it][1].x, rv[it][1].y};
                    f32x2 c01 = {rv[it][2].x, rv[it][2].y};
                    f32x2 d01 = {rv[it][3].x, rv[it][3].y};
                    f32x2 a23 = {rv[it][0].z, rv[it][0].w};
                    f32x2 b23 = {rv[it][1].z, rv[it][1].w};
                    f32x2 c23 = {rv[it][2].z, rv[it][2].w};
                    f32x2 d23 = {rv[it][3].z, rv[it][3].w};
                    f32x2 r01 = w4.x * a01 + w4.y * b01 + w4.z * c01 +
                                w4.w * d01;
                    f32x2 r23 = w4.x * a23 + w4.y * b23 + w4.z * c23 +
                                w4.w * d23;
                    uint2 pk;
                    pk.x = pk2h(r01.x, r01.y);
                    pk.y = pk2h(r23.x, r23.y);
                    *(uint2*)&samp[sp * 64 + swz(sp, sl16 << 2)] = pk;
                }
            }
        }
        f16x8 bfr[2];
#pragma unroll
        for (int ks = 0; ks < 2; ++ks)
            bfr[ks] = *(const f16x8*)&pwt[((((g * 9 + j) * 4 + wv) * 2 + ks)
                                           << 9) + lane * 8];
        __syncthreads();
        // ---- Phase A: depthwise 3x3 via packed f16 FMA, ch [fb, fb+16)
#pragma unroll
        for (int cq = 0; cq < 2; ++cq) {
            const int c8 = fb + (cq << 3);
            f16x2 d0 = {0, 0}, d1 = {0, 0}, d2 = {0, 0}, d3 = {0, 0};
#pragma unroll
            for (int t2 = 0; t2 < 9; ++t2) {
                const uint4 hv = *(const uint4*)&samp[aoff[t2][cq]];
                const uint4 wq =
                    *(const uint4*)&dwp[(((g * 9 + t2) * 9 + j) << 5) +
                                        (c8 >> 1)];
                d0 = u2h(hv.x) * u2h(wq.x) + d0;   // v_pk_fma_f16
                d1 = u2h(hv.y) * u2h(wq.y) + d1;
                d2 = u2h(hv.z) * u2h(wq.z) + d2;
                d3 = u2h(hv.w) * u2h(wq.w) + d3;
            }
            uint4 pk;
            pk.x = h2u(d0);
            pk.y = h2u(d1);
            pk.z = h2u(d2);
            pk.w = h2u(d3);
            *(uint4*)&dwa[p * 64 + swz(p, c8)] = pk;
        }
        __syncthreads();
        // ---- Phase B: pointwise via f16 MFMA
#pragma unroll
        for (int ks = 0; ks < 2; ++ks)
#pragma unroll
            for (int mt = 0; mt < 4; ++mt) {
                f16x8 af = *(const f16x8*)&dwa[boff[ks][mt]];
                acc[mt] = __builtin_amdgcn_mfma_f32_16x16x32_f16(
                    af, bfr[ks], acc[mt], 0, 0, 0);
            }
    }
    // ---- epilogue: C-layout col=lane&15, row=(lane>>4)*4+i
#pragma unroll
    for (int mt = 0; mt < 4; ++mt)
#pragma unroll
        for (int i = 0; i < 4; ++i) {
            int m = mt * 16 + rq + i;
            out[((b * HW + h0 + (m >> 3)) * HW + (w0 + (m & 7))) * 128 +
                (g << 6) + fb + col] = acc[mt][i];
        }
}

extern "C" void kernel_launch(void* const* d_in, const int* in_sizes, int n_in,
                              void* d_out, int out_size, void* d_ws,
                              size_t ws_size, hipStream_t stream) {
    const float* x = (const float*)d_in[0];
    const float* off_w = (const float*)d_in[1];
    const float* off_b = (const float*)d_in[2];
    const float* dw_w = (const float*)d_in[3];
    const float* dw_b = (const float*)d_in[4];
    const float* pw_w = (const float*)d_in[5];
    const float* pw_b = (const float*)d_in[6];

    // workspace layout (floats): [pwt | obt | dwp | bias2]
    float* wsf = (float*)d_ws;
    unsigned short* pwt = (unsigned short*)wsf;                // 147456 B
    unsigned short* obt = (unsigned short*)(wsf + PWT_FLOATS); // 147456 B
    unsigned* dwp = (unsigned*)(wsf + PWT_FLOATS + OBT_FLOATS);// 20736 B
    float* bias2 = wsf + PWT_FLOATS + OBT_FLOATS + DWP_WORDS;  // 512 B

    prep_kernel<<<dim3(28, GNUM), dim3(256), 0, stream>>>(pw_w, dw_b, off_w,
                                                          dw_w, pwt, obt, dwp,
                                                          bias2);
    deform_fused<<<dim3(BATCH * GNUM, 256), dim3(256), 0, stream>>>(
        x, obt, off_b, dwp, pwt, bias2, pw_b, (float*)d_out);
}

// Round 12
// 194.636 us; speedup vs baseline: 1.7822x; 1.1621x over previous
//
#include <hip/hip_runtime.h>
#include <hip/hip_bf16.h>

#define HW 128
#define GNUM 2
#define BATCH 4
#define OBT_STRIDE (GNUM * 18 * 2 * 512)       // shorts per hi/lo sub-buffer
#define PWT_FLOATS 36864                       // 73728 shorts (f16)
#define OBT_FLOATS 36864                       // 73728 shorts (hi+lo bf16)
#define DWP_WORDS 5184                         // 2g*9tap2*9j*32 u32 (f16x2)

typedef short s16x8 __attribute__((ext_vector_type(8)));
typedef _Float16 f16x8 __attribute__((ext_vector_type(8)));
typedef _Float16 f16x2 __attribute__((ext_vector_type(2)));
typedef __fp16 h16x2 __attribute__((ext_vector_type(2)));   // cvt_pkrtz ret type
typedef float f32x4 __attribute__((ext_vector_type(4)));
typedef float f32x2 __attribute__((ext_vector_type(2)));

__device__ inline unsigned short f2bf(float f) {
    union { float f; unsigned u; } v;
    v.f = f;
    unsigned r = (v.u + 0x7fffu + ((v.u >> 16) & 1u)) >> 16;
    return (unsigned short)r;
}
__device__ inline unsigned pk2bf(float lo, float hi) {   // v_cvt_pk_bf16_f32
    __hip_bfloat162 r = __float22bfloat162_rn(float2{lo, hi});
    return *(unsigned*)&r;
}
__device__ inline float blo(unsigned u) {
    union { unsigned u; float f; } v; v.u = u << 16; return v.f;
}
__device__ inline float bhi(unsigned u) {
    union { unsigned u; float f; } v; v.u = u & 0xffff0000u; return v.f;
}
__device__ inline unsigned short f2h(float f) {
    _Float16 h = (_Float16)f;
    return *(unsigned short*)&h;
}
__device__ inline unsigned pk2h(float lo, float hi) {    // v_cvt_pkrtz_f16_f32
    union { h16x2 h; unsigned u; } v;
    v.h = __builtin_amdgcn_cvt_pkrtz(lo, hi);
    return v.u;
}
__device__ inline f16x2 u2h(unsigned u) {
    union { unsigned u; f16x2 h; } v; v.u = u; return v.h;
}
__device__ inline unsigned h2u(f16x2 h) {
    union { unsigned u; f16x2 h; } v; v.h = h; return v.u;
}
// XOR-swizzle: permute 16B chunks within a 64-short row by (row + row/8) & 7.
__device__ inline int swz(int row, int off) {
    return (off & 7) | ((((off >> 3) ^ (row + (row >> 3))) & 7) << 3);
}

// ---------------------------------------------------------------------------
// prep_kernel (grid 28 x GNUM):
//   bx 0..8  -> pw_w -> f16 B-frags (pwt) + dwp f16x2 pack (validated).
//   bx 9..26 -> off_w -> bf16 hi/lo B-frags (validated).
//   bx 27    -> bias2 PARALLEL: 256 thr (4 quarters x 64 f), LDS reduce.
// ---------------------------------------------------------------------------
__global__ __launch_bounds__(256) void prep_kernel(
    const float* __restrict__ pw_w, const float* __restrict__ dw_b,
    const float* __restrict__ off_w, const float* __restrict__ dw_w,
    unsigned short* __restrict__ pwt, unsigned short* __restrict__ obt,
    unsigned* __restrict__ dwp, float* __restrict__ bias2) {
    const int g = blockIdx.y;
    const int t = threadIdx.x;
    if (blockIdx.x < 9) {
        const int j = blockIdx.x;
        const int wv = t >> 6, lane = t & 63;
        const int f = wv * 16 + (lane & 15);
        const int kbase = (lane >> 4) << 3;
#pragma unroll
        for (int ks = 0; ks < 2; ++ks)
#pragma unroll
            for (int i = 0; i < 8; ++i) {
                int kin = j * 64 + ks * 32 + kbase + i;
                pwt[((((g * 9 + j) * 4 + wv) * 2 + ks) << 9) + lane * 8 + i] =
                    f2h(pw_w[(g * 576 + kin) * 64 + f]);
            }
        for (int e = t; e < 288; e += 256) {
            int tap2 = e >> 5, cp = e & 31;
            const float* dwr = &dw_w[(g * 9 + tap2) * 576 + (j << 6) + cp * 2];
            dwp[(((g * 9 + tap2) * 9 + j) << 5) + cp] = pk2h(dwr[0], dwr[1]);
        }
    } else if (blockIdx.x < 27) {
        const int s = blockIdx.x - 9;
        const int tap = s >> 1;
        for (int e = t; e < 1024; e += 256) {
            int nt = e >> 9, le = e & 511;
            int lane = le >> 3, i = le & 7;
            int k = ((lane >> 4) << 3) + i;
            int c = ((s & 1) << 5) + k;
            int n = (nt << 4) + (lane & 15);
            float v = (n < 18) ? off_w[((g * 9 + tap) * 64 + c) * 18 + n] : 0.f;
            unsigned short hi = f2bf(v);
            unsigned short lo = f2bf(v - blo(hi));
            int idx = (((g * 18 + s) * 2 + nt) << 9) + le;
            obt[idx] = hi;
            obt[OBT_STRIDE + idx] = lo;
        }
    } else {
        __shared__ float red[256];
        const int f = t & 63, qd = t >> 6;
        float s = 0.f;
        for (int kin = qd * 144; kin < (qd + 1) * 144; ++kin)
            s += pw_w[(g * 576 + kin) * 64 + f] * dw_b[g * 576 + kin];
        red[qd * 64 + f] = s;
        __syncthreads();
        if (t < 64)
            bias2[g * 64 + t] =
                red[t] + red[64 + t] + red[128 + t] + red[192 + t];
    }
}

// ---------------------------------------------------------------------------
// deform_fused (R12 = R9 verbatim — best measured deform: ~125us, VGPR 52,
//   4 blocks/CU.  R10/R11 lesson: register-batched gather prefetch is
//   compiler-infeasible; do NOT retry).
// LDS 38,992 B -> 4 blocks/CU.
// ---------------------------------------------------------------------------
__global__ __launch_bounds__(256, 4) void deform_fused(
    const float* __restrict__ x, const unsigned short* __restrict__ obt,
    const float* __restrict__ off_b, const unsigned* __restrict__ dwp,
    const unsigned short* __restrict__ pwt, const float* __restrict__ bias2,
    const float* __restrict__ pw_b, float* __restrict__ out) {
    __shared__ char smem[38992];
    unsigned short* xh = (unsigned short*)smem;            // stage 0 only
    float* offs = (float*)smem;                            // epilogue only
    unsigned short* samp = (unsigned short*)smem;          // j-loop
    unsigned short* dwa = (unsigned short*)(smem + 12800); // j-loop
    float4* wlwAll = (float4*)(smem + 20992);
    unsigned* wliAll = (unsigned*)(smem + 35392);

    const int b = blockIdx.x >> 1, g = blockIdx.x & 1;
    const int tileIdx = blockIdx.y;
    const int h0 = (tileIdx >> 4) << 3, w0 = (tileIdx & 15) << 3;
    const int t = threadIdx.x;
    const int lane = t & 63;
    const int wv = __builtin_amdgcn_readfirstlane(t >> 6);
    const int kq = (lane >> 4) << 3;
    const int col = lane & 15;
    const int rq = (lane >> 4) << 2;

    // ================= Stage 0: offset conv for the halo =================
    f32x4 oacc[2][2];
#pragma unroll
    for (int sl = 0; sl < 2; ++sl)
#pragma unroll
        for (int nt = 0; nt < 2; ++nt) oacc[sl][nt] = (f32x4){0.f, 0.f, 0.f, 0.f};
    int mbase[2];
#pragma unroll
    for (int sl = 0; sl < 2; ++sl) {
        int mt = wv + (sl << 2);
        int m = mt * 16 + col;
        if (mt < 7 && m < 100) {
            int opy = m / 10, opx = m - opy * 10;
            mbase[sl] = opy * 12 + opx;
        } else
            mbase[sl] = 0;
    }
    for (int q = 0; q < 2; ++q) {
        if (q) __syncthreads();
        for (int idx = t; idx < 144 * 8; idx += 256) {
            int sp = idx >> 3, cq = idx & 7;
            int sy = sp / 12, sx = sp - sy * 12;
            int gy = h0 - 2 + sy, gx = w0 - 2 + sx;
            uint2 hp = {0, 0}, lp = {0, 0};
            if ((unsigned)gy < HW && (unsigned)gx < HW) {
                const float4 v = *(const float4*)&x[(((b * HW + gy) * HW + gx)
                                                    << 7) +
                                                   (g << 6) + (q << 5) + (cq << 2)];
                hp.x = pk2bf(v.x, v.y);
                hp.y = pk2bf(v.z, v.w);
                lp.x = pk2bf(v.x - blo(hp.x), v.y - bhi(hp.x));
                lp.y = pk2bf(v.z - blo(hp.y), v.w - bhi(hp.y));
            }
            *(uint2*)&xh[sp * 64 + swz(sp, cq << 2)] = hp;
            *(uint2*)&xh[sp * 64 + swz(sp, 32 + (cq << 2))] = lp;
        }
        __syncthreads();
        for (int tap = 0; tap < 9; ++tap) {
            const int s = (tap << 1) + q;
            const int ky = tap / 3, kx = tap - ky * 3;
            const int shift = ky * 12 + kx;
            const int bidx = ((g * 18 + s) << 1) << 9;
            s16x8 bh0 = *(const s16x8*)&obt[bidx + lane * 8];
            s16x8 bh1 = *(const s16x8*)&obt[bidx + 512 + lane * 8];
            s16x8 bl0 = *(const s16x8*)&obt[OBT_STRIDE + bidx + lane * 8];
            s16x8 bl1 = *(const s16x8*)&obt[OBT_STRIDE + bidx + 512 + lane * 8];
#pragma unroll
            for (int sl = 0; sl < 2; ++sl) {
                if (wv + (sl << 2) < 7) {   // wave-uniform guard
                    const int m2 = mbase[sl] + shift;
                    s16x8 ah = *(const s16x8*)&xh[m2 * 64 + swz(m2, kq)];
                    s16x8 al = *(const s16x8*)&xh[m2 * 64 + swz(m2, kq + 32)];
                    oacc[sl][0] = __builtin_amdgcn_mfma_f32_16x16x32_bf16(
                        ah, bh0, oacc[sl][0], 0, 0, 0);
                    oacc[sl][1] = __builtin_amdgcn_mfma_f32_16x16x32_bf16(
                        ah, bh1, oacc[sl][1], 0, 0, 0);
                    oacc[sl][0] = __builtin_amdgcn_mfma_f32_16x16x32_bf16(
                        al, bh0, oacc[sl][0], 0, 0, 0);
                    oacc[sl][1] = __builtin_amdgcn_mfma_f32_16x16x32_bf16(
                        al, bh1, oacc[sl][1], 0, 0, 0);
                    oacc[sl][0] = __builtin_amdgcn_mfma_f32_16x16x32_bf16(
                        ah, bl0, oacc[sl][0], 0, 0, 0);
                    oacc[sl][1] = __builtin_amdgcn_mfma_f32_16x16x32_bf16(
                        ah, bl1, oacc[sl][1], 0, 0, 0);
                }
            }
        }
    }
    __syncthreads();   // all xh reads done: offs aliases xh rows 0..56
    // write offs[m][o] = conv + off_b   (C-layout: row = rq+i, col)
#pragma unroll
    for (int sl = 0; sl < 2; ++sl) {
        int mt = wv + (sl << 2);
        if (mt < 7) {
#pragma unroll
            for (int nt = 0; nt < 2; ++nt) {
                int o = (nt << 4) + col;
                if (o < 18) {
                    float ob = off_b[g * 18 + o];
#pragma unroll
                    for (int i = 0; i < 4; ++i) {
                        int m = mt * 16 + rq + i;
                        if (m < 100) offs[m * 18 + o] = oacc[sl][nt][i] + ob;
                    }
                }
            }
        }
    }
    __syncthreads();   // offs visible
    // ---- W-precompute: bilinear weights + packed corners, ALL 9 taps ----
    for (int e = t; e < 900; e += 256) {
        const int jj = e / 100, sp = e - jj * 100;
        const int jy = jj / 3, jx = jj - jy * 3;
        const int spy = sp / 10, spx = sp - spy * 10;
        const int gy = h0 - 1 + spy, gx = w0 - 1 + spx;
        float4 w4 = {0.f, 0.f, 0.f, 0.f};
        unsigned wp = (unsigned)(b << 21);
        if ((unsigned)gy < HW && (unsigned)gx < HW) {
            const float ox = offs[sp * 18 + 2 * jj];
            const float oy = offs[sp * 18 + 2 * jj + 1];
            float xf = fminf(fmaxf((float)(gx + jx - 1) + ox, 0.f), 127.f);
            float yf = fminf(fmaxf((float)(gy + jy - 1) + oy, 0.f), 127.f);
            float x0 = floorf(xf), y0 = floorf(yf);
            float x1 = fminf(x0 + 1.f, 127.f);
            float y1 = fminf(y0 + 1.f, 127.f);
            w4.x = (x1 - xf) * (y1 - yf);
            w4.y = (x1 - xf) * (yf - y0);
            w4.z = (xf - x0) * (y1 - yf);
            w4.w = (xf - x0) * (yf - y0);
            const int x0i = (int)x0, y0i = (int)y0;
            wp = (unsigned)(((b * HW + y0i) * HW + x0i) << 7) |
                 (unsigned)((int)x1 - x0i) |
                 ((unsigned)((int)y1 - y0i) << 1);
        }
        wlwAll[jj * 100 + sp] = w4;
        wliAll[jj * 100 + sp] = wp;
    }
    __syncthreads();   // wlwAll/wliAll visible; offs dead

    // ================= Stage 1: sample -> depthwise -> pointwise =========
    const int fb = wv << 4;
    const int p = lane;
    const int ayp = p >> 3, axp = p & 7;
    const int grp = t >> 4, sl16 = t & 15;
    const int prow = ayp * 10 + axp;

    // hoisted j-invariant LDS offsets (static-indexed -> VGPRs)
    int aoff[9][2];
#pragma unroll
    for (int t2 = 0; t2 < 9; ++t2) {
        const int ky = t2 / 3, kx = t2 - ky * 3;
        const int row = prow + ky * 10 + kx;
#pragma unroll
        for (int cq = 0; cq < 2; ++cq)
            aoff[t2][cq] = row * 64 + swz(row, fb + (cq << 3));
    }
    int doff[2];
#pragma unroll
    for (int cq = 0; cq < 2; ++cq) doff[cq] = p * 64 + swz(p, fb + (cq << 3));
    int boff[2][4];
#pragma unroll
    for (int ks = 0; ks < 2; ++ks)
#pragma unroll
        for (int mt = 0; mt < 4; ++mt) {
            const int row = mt * 16 + col;
            boff[ks][mt] = row * 64 + swz(row, ks * 32 + kq);
        }
    int soff[7];
#pragma unroll
    for (int it = 0; it < 7; ++it) {
        const int sp_ = (it << 4) + grp;
        soff[it] = sp_ * 64 + swz(sp_, sl16 << 2);
    }

    const float bs = bias2[g * 64 + fb + col] + pw_b[g * 64 + fb + col];
    f32x4 acc[4];
#pragma unroll
    for (int mt = 0; mt < 4; ++mt) acc[mt] = (f32x4){bs, bs, bs, bs};

    for (int j = 0; j < 9; ++j) {
        f16x8 bfr[2];
#pragma unroll
        for (int ks = 0; ks < 2; ++ks)
            bfr[ks] = *(const f16x8*)&pwt[((((g * 9 + j) * 4 + wv) * 2 + ks)
                                           << 9) + lane * 8];
        // ---- Phase S: float4 gather; 16 lanes per sample; f32x2 blend
        for (int it = 0; it < 7; ++it) {
            const int sp = (it << 4) + grp;
            if (sp < 100) {
                const float4 w4 = wlwAll[j * 100 + sp];
                const unsigned wp = wliAll[j * 100 + sp];
                const float* xa = x + (wp & 0xFFFFFF80u) + (g << 6) +
                                  (sl16 << 2);
                const int xo = (int)((wp & 1u) << 7);
                const int yo = (int)((wp & 2u) << 13);
                const float4 va = *(const float4*)xa;
                const float4 vb = *(const float4*)(xa + yo);
                const float4 vc = *(const float4*)(xa + xo);
                const float4 vd = *(const float4*)(xa + xo + yo);
                f32x2 a01 = {va.x, va.y}, b01 = {vb.x, vb.y};
                f32x2 c01 = {vc.x, vc.y}, d01 = {vd.x, vd.y};
                f32x2 a23 = {va.z, va.w}, b23 = {vb.z, vb.w};
                f32x2 c23 = {vc.z, vc.w}, d23 = {vd.z, vd.w};
                f32x2 r01 = w4.x * a01 + w4.y * b01 + w4.z * c01 + w4.w * d01;
                f32x2 r23 = w4.x * a23 + w4.y * b23 + w4.z * c23 + w4.w * d23;
                uint2 pk;
                pk.x = pk2h(r01.x, r01.y);
                pk.y = pk2h(r23.x, r23.y);
                *(uint2*)&samp[soff[it]] = pk;
            }
        }
        __syncthreads();
        // ---- Phase A: depthwise 3x3 via packed f16 FMA, ch [fb, fb+16)
#pragma unroll
        for (int cq = 0; cq < 2; ++cq) {
            const int c8 = fb + (cq << 3);
            f16x2 d0 = {0, 0}, d1 = {0, 0}, d2 = {0, 0}, d3 = {0, 0};
#pragma unroll
            for (int t2 = 0; t2 < 9; ++t2) {
                const uint4 hv = *(const uint4*)&samp[aoff[t2][cq]];
                const uint4 wq =
                    *(const uint4*)&dwp[(((g * 9 + t2) * 9 + j) << 5) +
                                        (c8 >> 1)];
                d0 = u2h(hv.x) * u2h(wq.x) + d0;   // v_pk_fma_f16
                d1 = u2h(hv.y) * u2h(wq.y) + d1;
                d2 = u2h(hv.z) * u2h(wq.z) + d2;
                d3 = u2h(hv.w) * u2h(wq.w) + d3;
            }
            uint4 pk;
            pk.x = h2u(d0);
            pk.y = h2u(d1);
            pk.z = h2u(d2);
            pk.w = h2u(d3);
            *(uint4*)&dwa[doff[cq]] = pk;
        }
        __syncthreads();
        // ---- Phase B: pointwise via f16 MFMA
#pragma unroll
        for (int ks = 0; ks < 2; ++ks)
#pragma unroll
            for (int mt = 0; mt < 4; ++mt) {
                f16x8 af = *(const f16x8*)&dwa[boff[ks][mt]];
                acc[mt] = __builtin_amdgcn_mfma_f32_16x16x32_f16(
                    af, bfr[ks], acc[mt], 0, 0, 0);
            }
    }
    // ---- epilogue: C-layout col=lane&15, row=(lane>>4)*4+i
#pragma unroll
    for (int mt = 0; mt < 4; ++mt)
#pragma unroll
        for (int i = 0; i < 4; ++i) {
            int m = mt * 16 + rq + i;
            out[((b * HW + h0 + (m >> 3)) * HW + (w0 + (m & 7))) * 128 +
                (g << 6) + fb + col] = acc[mt][i];
        }
}

extern "C" void kernel_launch(void* const* d_in, const int* in_sizes, int n_in,
                              void* d_out, int out_size, void* d_ws,
                              size_t ws_size, hipStream_t stream) {
    const float* x = (const float*)d_in[0];
    const float* off_w = (const float*)d_in[1];
    const float* off_b = (const float*)d_in[2];
    const float* dw_w = (const float*)d_in[3];
    const float* dw_b = (const float*)d_in[4];
    const float* pw_w = (const float*)d_in[5];
    const float* pw_b = (const float*)d_in[6];

    // workspace layout (floats): [pwt | obt | dwp | bias2]
    float* wsf = (float*)d_ws;
    unsigned short* pwt = (unsigned short*)wsf;                // 147456 B
    unsigned short* obt = (unsigned short*)(wsf + PWT_FLOATS); // 147456 B
    unsigned* dwp = (unsigned*)(wsf + PWT_FLOATS + OBT_FLOATS);// 20736 B
    float* bias2 = wsf + PWT_FLOATS + OBT_FLOATS + DWP_WORDS;  // 512 B

    prep_kernel<<<dim3(28, GNUM), dim3(256), 0, stream>>>(pw_w, dw_b, off_w,
                                                          dw_w, pwt, obt, dwp,
                                                          bias2);
    deform_fused<<<dim3(BATCH * GNUM, 256), dim3(256), 0, stream>>>(
        x, obt, off_b, dwp, pwt, bias2, pw_b, (float*)d_out);
}